// Round 11
// baseline (41378.650 us; speedup 1.0000x reference)
//
#include <hip/hip_runtime.h>
#include <math.h>

// Problem constants
#define BB 16
#define TT 128
#define F_IN 240
#define E_DIM 1024
#define HH 320
#define G4 1280
#define JHD 512
#define VV 29
#define BLANKV 28
#define MAXSYM 3
#define LBUF (TT*MAXSYM)

#define GROUPS 8
#define RPG 20            // roles per group
#define NLAUNCH 256       // launched blocks (1/CU, 32/XCD guaranteed)
#define HR 16             // h-rows per role (320/20)
#define JR 32             // joint rows per C-role
#define CROLES 16         // roles doing phase C (16*32=512)

// Workspace layout (float offsets)
#define OFF_FPROJ 0ul                        // 2048*512
#define OFF_WJHR  1048576ul                  // 512*320
#define OFF_EP    (OFF_WJHR + 163840ul)      // 29*1280
#define OFF_B1    (OFF_EP + 37120ul)         // 1280
#define OFF_WJ2T  (OFF_B1 + 1280ul)          // 29*512 = 14848
#define OFF_MA    (OFF_WJ2T + 14848ul)       // [8][2][320] = 5120
#define OFF_MB    (OFF_MA + 5120ul)          // 5120
#define OFF_JH    (OFF_MB + 5120ul)          // [8][2][512] = 8192
#define OFF_SYNC  (OFF_JH + 8192ul)          // 2048 ints

typedef float f32x4 __attribute__((ext_vector_type(4)));

__device__ __forceinline__ float sigmoidf_(float x) {
    return 1.0f / (1.0f + expf(-x));
}
// LLC-scope (agent) tag ops
__device__ __forceinline__ int ld_tag(const int* p) {
    return __hip_atomic_load(p, __ATOMIC_RELAXED, __HIP_MEMORY_SCOPE_AGENT);
}
__device__ __forceinline__ void st_tag(int* p, int v) {
    __hip_atomic_store(p, v, __ATOMIC_RELAXED, __HIP_MEMORY_SCOPE_AGENT);
}
// XCD-L2-scope ops (sc0: bypass L1; L1 is write-through so stores land in L2)
__device__ __forceinline__ int ld_sc0_i(const int* p) {
    int v;
    asm volatile("global_load_dword %0, %1, off sc0\n\ts_waitcnt vmcnt(0)"
                 : "=v"(v) : "v"(p) : "memory");
    return v;
}
__device__ __forceinline__ void st_sc0_i(int* p, int v) {
    asm volatile("global_store_dword %0, %1, off sc0" :: "v"(p), "v"(v) : "memory");
}
// data ops: pure group -> sc0 (XCD-local L2); impure -> sc0 sc1 (LLC)
__device__ __forceinline__ void st_data_f(float* p, float v, int pure) {
    if (pure) asm volatile("global_store_dword %0, %1, off sc0" :: "v"(p), "v"(v) : "memory");
    else      asm volatile("global_store_dword %0, %1, off sc0 sc1" :: "v"(p), "v"(v) : "memory");
}
__device__ __forceinline__ f32x4 ld4_data(const float* p, int pure) {
    f32x4 v;
    if (pure) asm volatile("global_load_dwordx4 %0, %1, off sc0\n\ts_waitcnt vmcnt(0)"
                           : "=&v"(v) : "v"(p) : "memory");
    else      asm volatile("global_load_dwordx4 %0, %1, off sc0 sc1\n\ts_waitcnt vmcnt(0)"
                           : "=&v"(v) : "v"(p) : "memory");
    return v;
}
// wave-0 poll: fast sc0 tags, slow LLC tags checked every 256 iters (insurance)
__device__ __forceinline__ void poll_tags(const int* fastT, const int* slowT,
                                          int n, int e) {
    int lane = threadIdx.x;   // caller guarantees tid < 64
    int it = 0;
    while (true) {
        bool ny = (lane < n) && (ld_sc0_i(fastT + lane) < e);
        if (__ballot(ny) == 0ull) return;
        if (((++it) & 255) == 0) {
            bool ny2 = (lane < n) && (ld_tag(slowT + lane) < e);
            if (__ballot(ny2) == 0ull) return;
        }
    }
}

// ---- Prep: WjhR[j][k]=Wj1[1024+k][j]; b1=bih1+bhh1; Wj2T[v][k]=Wj2[k][v] ----
__global__ void prep_t_kernel(const float* __restrict__ Wj1,
                              const float* __restrict__ bih1,
                              const float* __restrict__ bhh1,
                              const float* __restrict__ Wj2,
                              float* __restrict__ WjhR, float* __restrict__ b1,
                              float* __restrict__ Wj2T) {
    int idx = blockIdx.x * 256 + threadIdx.x;
    if (idx < 163840) {
        int j = idx / 320, k = idx - j * 320;
        WjhR[idx] = Wj1[(size_t)(1024 + k) * JHD + j];
        return;
    }
    int i2 = idx - 163840;
    if (i2 < G4) { b1[i2] = bih1[i2] + bhh1[i2]; return; }
    int e = i2 - G4;
    if (e < VV * JHD) {
        int v = e >> 9, k = e & 511;
        Wj2T[e] = Wj2[(size_t)k * VV + v];
    }
}

// ---- Prep: EP[v][j] = embed[v]@Wih0[j,:] + bih0[j]+bhh0[j]; row 28 = bias only
__global__ void ep_kernel(const float* __restrict__ embed,
                          const float* __restrict__ Wih0,
                          const float* __restrict__ bih0,
                          const float* __restrict__ bhh0,
                          float* __restrict__ EP) {
    __shared__ __align__(16) float es[HH];
    int v = blockIdx.x;
    for (int k = threadIdx.x; k < HH; k += 256)
        es[k] = (v < VV - 1) ? embed[v * HH + k] : 0.0f;
    __syncthreads();
    for (int j = threadIdx.x; j < G4; j += 256) {
        float acc = bih0[j] + bhh0[j];
        if (v < VV - 1) {
            const float4* wr = (const float4*)(Wih0 + (size_t)j * HH);
            const float4* ev = (const float4*)es;
            #pragma unroll 4
            for (int k4 = 0; k4 < HH / 4; ++k4) {
                float4 w = wr[k4], e = ev[k4];
                acc += w.x * e.x + w.y * e.y + w.z * e.z + w.w * e.w;
            }
        }
        EP[v * G4 + j] = acc;
    }
}

// ---- Encoder + F_proj fused ----
__global__ __launch_bounds__(512) void enc_fproj_kernel(
    const float* __restrict__ x, const float* __restrict__ Wenc,
    const float* __restrict__ benc, const float* __restrict__ Wj1,
    const float* __restrict__ bj1,
    float* __restrict__ logits_out, float* __restrict__ Fproj) {
    __shared__ float xs[8][F_IN];
    __shared__ float ls[8][E_DIM];
    int row0 = blockIdx.x * 8;
    int tid = threadIdx.x;
    for (int i = tid; i < 8 * F_IN; i += 512)
        xs[i / F_IN][i % F_IN] = x[(size_t)row0 * F_IN + i];
    __syncthreads();
    for (int j = tid; j < E_DIM; j += 512) {
        float acc[8];
        float bv = benc[j];
        #pragma unroll
        for (int r = 0; r < 8; ++r) acc[r] = bv;
        for (int k = 0; k < F_IN; ++k) {
            float w = Wenc[(size_t)k * E_DIM + j];
            #pragma unroll
            for (int r = 0; r < 8; ++r) acc[r] += xs[r][k] * w;
        }
        #pragma unroll
        for (int r = 0; r < 8; ++r) {
            ls[r][j] = acc[r];
            logits_out[(size_t)(row0 + r) * E_DIM + j] = acc[r];
        }
    }
    __syncthreads();
    {
        int j = tid;
        float acc[8];
        float bv = bj1[j];
        #pragma unroll
        for (int r = 0; r < 8; ++r) acc[r] = bv;
        for (int k = 0; k < E_DIM; ++k) {
            float w = Wj1[(size_t)k * JHD + j];
            #pragma unroll
            for (int r = 0; r < 8; ++r) acc[r] += ls[r][k] * w;
        }
        #pragma unroll
        for (int r = 0; r < 8; ++r) Fproj[(size_t)(row0 + r) * JHD + j] = acc[r];
    }
}

// ---- Init: zero sync; labels=-1; out_lens passthrough ----
__global__ void init_kernel(const int* __restrict__ lens, float* ws,
                            float* __restrict__ out_lens_out,
                            float* __restrict__ labels_out) {
    int tid = threadIdx.x;
    int* sync = (int*)(ws + OFF_SYNC);
    for (int i = tid; i < 2048; i += 1024) sync[i] = 0;
    for (int i = tid; i < BB * LBUF; i += 1024) labels_out[i] = -1.0f;
    if (tid < BB) out_lens_out[tid] = (float)lens[tid];
}

// ---- 8 per-XCD groups x 20 roles; 256 launched (32/XCD -> always pure);
// fast sc0 tags + LLC fallback tags; replicated local phase D. ----
__global__ __launch_bounds__(1024) void decode_persistent(
    const int* __restrict__ lens,
    const float* __restrict__ Fproj,
    const float* __restrict__ W0,    // Whh0 [1280][320]
    const float* __restrict__ W1a,   // Wih1 [1280][320]
    const float* __restrict__ W1b,   // Whh1 [1280][320]
    const float* __restrict__ WjhR,  // [512][320]
    const float* __restrict__ Wj2T,  // [29][512]
    const float* __restrict__ EP, const float* __restrict__ b1,
    const float* __restrict__ bj2,
    float* MA, float* MB, float* JH, int* syncw,
    float* __restrict__ labels_out, float* __restrict__ counts_out) {

    const int tid = threadIdx.x;
    int* cntw  = syncw;           // [8], stride 16 ints
    int* arrw  = syncw + 128;
    int* tagsF = syncw + 256;     // fast: [8][3][32]
    int* tagsS = syncw + 1024;    // slow: [8][3][32]

    // ---------- formation: ticket local XCD, rendezvous(256), fill deficits ----------
    __shared__ int sGrp, sRole, sPure;
    if (tid == 0) {
        unsigned xr;
        asm volatile("s_getreg_b32 %0, hwreg(HW_REG_XCC_ID)" : "=s"(xr));
        int xcc = (int)(xr & 7u);
        int tkt = atomicAdd(cntw + xcc * 16, 1);
        asm volatile("s_waitcnt vmcnt(0)" ::: "memory");
        atomicAdd(arrw, 1);
        while (__hip_atomic_load(arrw, __ATOMIC_RELAXED, __HIP_MEMORY_SCOPE_AGENT) < NLAUNCH) { }
        int c[8];
        #pragma unroll
        for (int h = 0; h < 8; ++h)
            c[h] = __hip_atomic_load(cntw + h * 16, __ATOMIC_RELAXED,
                                     __HIP_MEMORY_SCOPE_AGENT);
        int grp = -1, role = 0;
        if (tkt < RPG) { grp = xcc; role = tkt; }
        else {
            int ov = tkt - RPG;
            for (int h = 0; h < xcc; ++h) ov += max(0, c[h] - RPG);
            int acc = 0;
            for (int g2 = 0; g2 < 8; ++g2) {
                int granted = min(c[g2], RPG);
                int d = RPG - granted;
                if (grp < 0 && ov < acc + d) { grp = g2; role = granted + (ov - acc); }
                acc += d;
            }
        }
        sGrp = grp; sRole = role;
        sPure = (grp >= 0 && c[grp] >= RPG) ? 1 : 0;
    }
    __syncthreads();
    const int grp = sGrp, role = sRole, pure = sPure;
    if (grp < 0) return;   // surplus block

    float* MAg = MA + grp * 640;
    float* MBg = MB + grp * 640;
    float* JHg = JH + grp * 1024;
    int* fA = tagsF + grp * 96;   int* sA = tagsS + grp * 96;
    int* fB = fA + 32;            int* sB = sA + 32;
    int* fC = fA + 64;            int* sC = sA + 64;

    extern __shared__ float dyn[];
    float* h0c = dyn;            // [2][320]
    float* h1c = dyn + 640;
    float* h0p = dyn + 1280;
    float* h1p = dyn + 1920;
    float* jhl = dyn + 2560;     // [2][512]

    __shared__ float gA[128], gB[128], lgL[64];
    __shared__ int lastL[2], cntL[2], contL[2], lenL[2], emitL[2];

    for (int i = tid; i < 640; i += 1024) { h0c[i] = 0.f; h1c[i] = 0.f; }
    if (tid < 2) {
        lastL[tid] = BLANKV; cntL[tid] = 0; contL[tid] = 0;
        lenL[tid] = lens[2 * grp + tid];
    }
    __syncthreads();
    const int maxL = max(lenL[0], lenL[1]);

    // matvec lanes: item(b0) | ks(b1-3) | r(b4-9)
    const int item = tid & 1;
    const int ks   = (tid >> 1) & 7;
    const int r    = tid >> 4;            // 0..63 local gate row
    const int gg   = r >> 4, rl = r & 15;
    const int hrow = role * HR + rl;      // 0..319
    const int kf   = ks * 40;
    const size_t wrow = (size_t)(gg * HH + hrow) * HH + kf;

    float c0cur = 0.f, c1cur = 0.f, c0p = 0.f, c1p = 0.f;

    for (int slot = 0; slot < 3 * maxL; ++slot) {
        const int t = slot / 3;
        const int s = slot - t * 3;
        const int e = slot + 1;

        // ===== Phase A: gates0 = Whh0@h0c (+EP); gB = Whh1@h1c partial =====
        {
            float a0 = 0.f, ab = 0.f;
            const f32x4* h0 = (const f32x4*)(h0c + item * HH + kf);
            const f32x4* h1 = (const f32x4*)(h1c + item * HH + kf);
            #pragma unroll
            for (int u = 0; u < 10; ++u) {
                f32x4 w  = *(const f32x4*)(W0 + wrow + u * 4);
                f32x4 h  = h0[u];
                a0 += w[0]*h[0] + w[1]*h[1] + w[2]*h[2] + w[3]*h[3];
                f32x4 w2 = *(const f32x4*)(W1b + wrow + u * 4);
                f32x4 h2 = h1[u];
                ab += w2[0]*h2[0] + w2[1]*h2[1] + w2[2]*h2[2] + w2[3]*h2[3];
            }
            a0 += __shfl_xor(a0, 2); a0 += __shfl_xor(a0, 4); a0 += __shfl_xor(a0, 8);
            ab += __shfl_xor(ab, 2); ab += __shfl_xor(ab, 4); ab += __shfl_xor(ab, 8);
            if (ks == 0) {
                gA[item * 64 + r] = a0 + EP[(size_t)lastL[item] * G4 + gg * HH + hrow];
                gB[item * 64 + r] = ab;
            }
        }
        __syncthreads();
        if (tid < 32) {
            int it = tid & 1, hr = tid >> 1;
            float xi = gA[it * 64 + hr];
            float xf = gA[it * 64 + 16 + hr];
            float xg = gA[it * 64 + 32 + hr];
            float xo = gA[it * 64 + 48 + hr];
            c0p = sigmoidf_(xf) * c0cur + sigmoidf_(xi) * tanhf(xg);
            st_data_f(MAg + it * HH + role * HR + hr, sigmoidf_(xo) * tanhf(c0p), pure);
        }
        asm volatile("s_waitcnt vmcnt(0)" ::: "memory");
        __syncthreads();
        if (tid == 0) { st_sc0_i(fA + role, e); st_tag(sA + role, e); }

        // ===== poll A + stage MA -> h0p =====
        if (tid < 64) poll_tags(fA, sA, RPG, e);
        __syncthreads();
        if (tid < 160) {
            f32x4 v = ld4_data(MAg + tid * 4, pure);
            int it = tid / 80, k = tid * 4 - it * 320;
            *(f32x4*)(h0p + it * HH + k) = v;
        }
        __syncthreads();

        // ===== Phase B: gates1 = Wih1@h0p + gB + b1 =====
        {
            float a1 = 0.f;
            const f32x4* hv = (const f32x4*)(h0p + item * HH + kf);
            #pragma unroll
            for (int u = 0; u < 10; ++u) {
                f32x4 w = *(const f32x4*)(W1a + wrow + u * 4);
                f32x4 h = hv[u];
                a1 += w[0]*h[0] + w[1]*h[1] + w[2]*h[2] + w[3]*h[3];
            }
            a1 += __shfl_xor(a1, 2); a1 += __shfl_xor(a1, 4); a1 += __shfl_xor(a1, 8);
            if (ks == 0)
                gA[item * 64 + r] = a1 + gB[item * 64 + r] + b1[gg * HH + hrow];
        }
        __syncthreads();
        if (tid < 32) {
            int it = tid & 1, hr = tid >> 1;
            float xi = gA[it * 64 + hr];
            float xf = gA[it * 64 + 16 + hr];
            float xg = gA[it * 64 + 32 + hr];
            float xo = gA[it * 64 + 48 + hr];
            c1p = sigmoidf_(xf) * c1cur + sigmoidf_(xi) * tanhf(xg);
            st_data_f(MBg + it * HH + role * HR + hr, sigmoidf_(xo) * tanhf(c1p), pure);
        }
        asm volatile("s_waitcnt vmcnt(0)" ::: "memory");
        __syncthreads();
        if (tid == 0) { st_sc0_i(fB + role, e); st_tag(sB + role, e); }

        // ===== poll B + stage MB -> h1p =====
        if (tid < 64) poll_tags(fB, sB, RPG, e);
        __syncthreads();
        if (tid < 160) {
            f32x4 v = ld4_data(MBg + tid * 4, pure);
            int it = tid / 80, k = tid * 4 - it * 320;
            *(f32x4*)(h1p + it * HH + k) = v;
        }
        __syncthreads();

        // ===== Phase C (roles 0..15): jh = relu(Fproj + Wjh@h1p) =====
        if (role < CROLES && tid < 512) {
            int jl = tid >> 4;                   // 0..31
            int jg2 = role * JR + jl;            // 0..511
            float a = 0.f;
            const f32x4* hv = (const f32x4*)(h1p + item * HH + kf);
            const float* wc = WjhR + (size_t)jg2 * HH + kf;
            #pragma unroll
            for (int u = 0; u < 10; ++u) {
                f32x4 w = *(const f32x4*)(wc + u * 4);
                f32x4 h = hv[u];
                a += w[0]*h[0] + w[1]*h[1] + w[2]*h[2] + w[3]*h[3];
            }
            a += __shfl_xor(a, 2); a += __shfl_xor(a, 4); a += __shfl_xor(a, 8);
            if (ks == 0) {
                float fp = Fproj[((size_t)(2 * grp + item) * TT + t) * JHD + jg2];
                st_data_f(JHg + item * JHD + jg2, fmaxf(a + fp, 0.f), pure);
            }
        }
        asm volatile("s_waitcnt vmcnt(0)" ::: "memory");
        __syncthreads();
        if (role < CROLES && tid == 0) { st_sc0_i(fC + role, e); st_tag(sC + role, e); }

        // ===== poll C + stage JH -> jhl =====
        if (tid < 64) poll_tags(fC, sC, CROLES, e);
        __syncthreads();
        if (tid < 256) {
            f32x4 v = ld4_data(JHg + tid * 4, pure);
            int it = tid / 128, k = tid * 4 - it * 512;
            *(f32x4*)(jhl + it * JHD + k) = v;
        }
        __syncthreads();

        // ===== Phase D (replicated): logits + argmax + commit =====
        if (tid < 928) {
            int k4 = tid & 15, it2 = (tid >> 4) & 1, v = tid >> 5;  // v 0..28
            const float* wv = Wj2T + (size_t)v * JHD + k4 * 32;
            const f32x4* hj = (const f32x4*)(jhl + it2 * JHD + k4 * 32);
            float a = 0.f;
            #pragma unroll
            for (int u2 = 0; u2 < 8; ++u2) {
                f32x4 w = *(const f32x4*)(wv + u2 * 4);
                f32x4 h = hj[u2];
                a += w[0]*h[0] + w[1]*h[1] + w[2]*h[2] + w[3]*h[3];
            }
            a += __shfl_xor(a, 1); a += __shfl_xor(a, 2);
            a += __shfl_xor(a, 4); a += __shfl_xor(a, 8);
            if (k4 == 0) lgL[it2 * 32 + v] = a + bj2[v];
        }
        __syncthreads();
        if (tid < 2) {
            float best = lgL[tid * 32];
            int k = 0;
            #pragma unroll
            for (int v = 1; v < VV; ++v) {
                float x = lgL[tid * 32 + v];
                if (x > best) { best = x; k = v; }
            }
            bool active = (t < lenL[tid]) && (s == 0 || contL[tid]);
            bool emit = active && (k != BLANKV);
            emitL[tid] = emit ? 1 : 0;
            if (emit) {
                if (role == 0)
                    labels_out[(size_t)(2 * grp + tid) * LBUF + cntL[tid]] = (float)k;
                cntL[tid]++; lastL[tid] = k; contL[tid] = 1;
            } else {
                contL[tid] = 0;
            }
        }
        __syncthreads();
        // commit: LDS copy of pending state; private c registers
        if (tid < 640) {
            int it = tid / 320, k = tid - it * 320;
            if (emitL[it]) {
                h0c[it * HH + k] = h0p[it * HH + k];
                h1c[it * HH + k] = h1p[it * HH + k];
            }
        }
        if (tid < 32 && emitL[tid & 1]) { c0cur = c0p; c1cur = c1p; }
        __syncthreads();
    }

    if (role == 0 && tid < 2) counts_out[2 * grp + tid] = (float)cntL[tid];
}

extern "C" void kernel_launch(void* const* d_in, const int* in_sizes, int n_in,
                              void* d_out, int out_size, void* d_ws, size_t ws_size,
                              hipStream_t stream) {
    const float* x      = (const float*)d_in[0];
    const int*   lens   = (const int*)d_in[1];
    const float* Wenc   = (const float*)d_in[2];
    const float* benc   = (const float*)d_in[3];
    const float* embed  = (const float*)d_in[4];
    const float* Wih0   = (const float*)d_in[5];
    const float* Whh0   = (const float*)d_in[6];
    const float* bih0   = (const float*)d_in[7];
    const float* bhh0   = (const float*)d_in[8];
    const float* Wih1   = (const float*)d_in[9];
    const float* Whh1   = (const float*)d_in[10];
    const float* bih1   = (const float*)d_in[11];
    const float* bhh1   = (const float*)d_in[12];
    const float* Wj1    = (const float*)d_in[13];
    const float* bj1    = (const float*)d_in[14];
    const float* Wj2    = (const float*)d_in[15];
    const float* bj2    = (const float*)d_in[16];

    float* out = (float*)d_out;
    float* logits_out   = out;
    float* out_lens_out = out + (size_t)BB * TT * E_DIM;
    float* labels_out   = out_lens_out + BB;
    float* counts_out   = labels_out + (size_t)BB * LBUF;

    float* ws    = (float*)d_ws;
    float* Fproj = ws + OFF_FPROJ;
    float* WjhR  = ws + OFF_WJHR;
    float* EP    = ws + OFF_EP;
    float* b1    = ws + OFF_B1;
    float* Wj2T  = ws + OFF_WJ2T;
    float* MA    = ws + OFF_MA;
    float* MB    = ws + OFF_MB;
    float* JH    = ws + OFF_JH;
    int*   syncw = (int*)(ws + OFF_SYNC);

    // Force 1 block/CU -> exactly 32 blocks/XCD -> every group pure
    const int dynBytes = 84 * 1024;
    hipFuncSetAttribute((const void*)decode_persistent,
                        hipFuncAttributeMaxDynamicSharedMemorySize, dynBytes);

    {
        int total = 163840 + G4 + VV * JHD;
        prep_t_kernel<<<(total + 255) / 256, 256, 0, stream>>>(
            Wj1, bih1, bhh1, Wj2, WjhR, b1, Wj2T);
    }
    ep_kernel<<<VV, 256, 0, stream>>>(embed, Wih0, bih0, bhh0, EP);
    enc_fproj_kernel<<<(BB * TT) / 8, 512, 0, stream>>>(x, Wenc, benc, Wj1, bj1,
                                                        logits_out, Fproj);
    init_kernel<<<1, 1024, 0, stream>>>(lens, ws, out_lens_out, labels_out);
    decode_persistent<<<NLAUNCH, 1024, dynBytes, stream>>>(
        lens, Fproj, Whh0, Wih1, Whh1, WjhR, Wj2T, EP, b1, bj2,
        MA, MB, JH, syncw, labels_out, counts_out);
}

// Round 12
// 18390.054 us; speedup vs baseline: 2.2501x; 2.2501x over previous
//
#include <hip/hip_runtime.h>
#include <math.h>

// Problem constants
#define BB 16
#define TT 128
#define F_IN 240
#define E_DIM 1024
#define HH 320
#define G4 1280
#define JHD 512
#define VV 29
#define BLANKV 28
#define MAXSYM 3
#define LBUF (TT*MAXSYM)

#define GROUPS 8
#define RPG 20            // roles per group
#define NLAUNCH 256       // launched blocks (1/CU, 32/XCD guaranteed)
#define HR 16             // h-rows per role (320/20)
#define JR 32             // joint rows per C-role
#define CROLES 16         // roles doing phase C (16*32=512)

// Workspace layout (float offsets)
#define OFF_FPROJ 0ul                        // 2048*512
#define OFF_WJHR  1048576ul                  // 512*320
#define OFF_EP    (OFF_WJHR + 163840ul)      // 29*1280
#define OFF_B1    (OFF_EP + 37120ul)         // 1280
#define OFF_WJ2T  (OFF_B1 + 1280ul)          // 29*512 = 14848
#define OFF_MA    (OFF_WJ2T + 14848ul)       // [8][2][320] = 5120
#define OFF_MB    (OFF_MA + 5120ul)          // 5120
#define OFF_JH    (OFF_MB + 5120ul)          // [8][2][512] = 8192
#define OFF_SYNC  (OFF_JH + 8192ul)          // 2048 ints

typedef float f32x4 __attribute__((ext_vector_type(4)));

__device__ __forceinline__ float sigmoidf_(float x) {
    return 1.0f / (1.0f + expf(-x));
}
// LLC-scope (agent) tag ops
__device__ __forceinline__ int ld_tag(const int* p) {
    return __hip_atomic_load(p, __ATOMIC_RELAXED, __HIP_MEMORY_SCOPE_AGENT);
}
__device__ __forceinline__ void st_tag(int* p, int v) {
    __hip_atomic_store(p, v, __ATOMIC_RELAXED, __HIP_MEMORY_SCOPE_AGENT);
}
// XCD-L2-scope ops (sc0: bypass L1, hit the XCD's shared L2)
__device__ __forceinline__ int ld_sc0_i(const int* p) {
    int v;
    asm volatile("global_load_dword %0, %1, off sc0\n\ts_waitcnt vmcnt(0)"
                 : "=v"(v) : "v"(p) : "memory");
    return v;
}
__device__ __forceinline__ void st_sc0_i(int* p, int v) {
    asm volatile("global_store_dword %0, %1, off sc0" :: "v"(p), "v"(v) : "memory");
}
// data ops: pure group -> sc0 (XCD-local L2); impure -> sc0 sc1 (LLC)
__device__ __forceinline__ void st_data_f(float* p, float v, int pure) {
    if (pure) asm volatile("global_store_dword %0, %1, off sc0" :: "v"(p), "v"(v) : "memory");
    else      asm volatile("global_store_dword %0, %1, off sc0 sc1" :: "v"(p), "v"(v) : "memory");
}
__device__ __forceinline__ f32x4 ld4_data(const float* p, int pure) {
    f32x4 v;
    if (pure) asm volatile("global_load_dwordx4 %0, %1, off sc0\n\ts_waitcnt vmcnt(0)"
                           : "=&v"(v) : "v"(p) : "memory");
    else      asm volatile("global_load_dwordx4 %0, %1, off sc0 sc1\n\ts_waitcnt vmcnt(0)"
                           : "=&v"(v) : "v"(p) : "memory");
    return v;
}
// wave-0 poll: fast sc0 tags with backoff; slow LLC tags every 64 iters
__device__ __forceinline__ void poll_tags(const int* fastT, const int* slowT,
                                          int n, int e) {
    int lane = threadIdx.x;   // caller guarantees tid < 64
    int it = 0;
    while (true) {
        bool ny = (lane < n) && (ld_sc0_i(fastT + lane) < e);
        if (__ballot(ny) == 0ull) return;
        if (((++it) & 63) == 0) {
            bool ny2 = (lane < n) && (ld_tag(slowT + lane) < e);
            if (__ballot(ny2) == 0ull) return;
        }
        __builtin_amdgcn_s_sleep(1);
    }
}

// ---- Prep: WjhR[j][k]=Wj1[1024+k][j]; b1=bih1+bhh1; Wj2T[v][k]=Wj2[k][v] ----
__global__ void prep_t_kernel(const float* __restrict__ Wj1,
                              const float* __restrict__ bih1,
                              const float* __restrict__ bhh1,
                              const float* __restrict__ Wj2,
                              float* __restrict__ WjhR, float* __restrict__ b1,
                              float* __restrict__ Wj2T) {
    int idx = blockIdx.x * 256 + threadIdx.x;
    if (idx < 163840) {
        int j = idx / 320, k = idx - j * 320;
        WjhR[idx] = Wj1[(size_t)(1024 + k) * JHD + j];
        return;
    }
    int i2 = idx - 163840;
    if (i2 < G4) { b1[i2] = bih1[i2] + bhh1[i2]; return; }
    int e = i2 - G4;
    if (e < VV * JHD) {
        int v = e >> 9, k = e & 511;
        Wj2T[e] = Wj2[(size_t)k * VV + v];
    }
}

// ---- Prep: EP[v][j] = embed[v]@Wih0[j,:] + bih0[j]+bhh0[j]; row 28 = bias only
__global__ void ep_kernel(const float* __restrict__ embed,
                          const float* __restrict__ Wih0,
                          const float* __restrict__ bih0,
                          const float* __restrict__ bhh0,
                          float* __restrict__ EP) {
    __shared__ __align__(16) float es[HH];
    int v = blockIdx.x;
    for (int k = threadIdx.x; k < HH; k += 256)
        es[k] = (v < VV - 1) ? embed[v * HH + k] : 0.0f;
    __syncthreads();
    for (int j = threadIdx.x; j < G4; j += 256) {
        float acc = bih0[j] + bhh0[j];
        if (v < VV - 1) {
            const float4* wr = (const float4*)(Wih0 + (size_t)j * HH);
            const float4* ev = (const float4*)es;
            #pragma unroll 4
            for (int k4 = 0; k4 < HH / 4; ++k4) {
                float4 w = wr[k4], e = ev[k4];
                acc += w.x * e.x + w.y * e.y + w.z * e.z + w.w * e.w;
            }
        }
        EP[v * G4 + j] = acc;
    }
}

// ---- Encoder + F_proj fused ----
__global__ __launch_bounds__(512) void enc_fproj_kernel(
    const float* __restrict__ x, const float* __restrict__ Wenc,
    const float* __restrict__ benc, const float* __restrict__ Wj1,
    const float* __restrict__ bj1,
    float* __restrict__ logits_out, float* __restrict__ Fproj) {
    __shared__ float xs[8][F_IN];
    __shared__ float ls[8][E_DIM];
    int row0 = blockIdx.x * 8;
    int tid = threadIdx.x;
    for (int i = tid; i < 8 * F_IN; i += 512)
        xs[i / F_IN][i % F_IN] = x[(size_t)row0 * F_IN + i];
    __syncthreads();
    for (int j = tid; j < E_DIM; j += 512) {
        float acc[8];
        float bv = benc[j];
        #pragma unroll
        for (int r = 0; r < 8; ++r) acc[r] = bv;
        for (int k = 0; k < F_IN; ++k) {
            float w = Wenc[(size_t)k * E_DIM + j];
            #pragma unroll
            for (int r = 0; r < 8; ++r) acc[r] += xs[r][k] * w;
        }
        #pragma unroll
        for (int r = 0; r < 8; ++r) {
            ls[r][j] = acc[r];
            logits_out[(size_t)(row0 + r) * E_DIM + j] = acc[r];
        }
    }
    __syncthreads();
    {
        int j = tid;
        float acc[8];
        float bv = bj1[j];
        #pragma unroll
        for (int r = 0; r < 8; ++r) acc[r] = bv;
        for (int k = 0; k < E_DIM; ++k) {
            float w = Wj1[(size_t)k * JHD + j];
            #pragma unroll
            for (int r = 0; r < 8; ++r) acc[r] += ls[r][k] * w;
        }
        #pragma unroll
        for (int r = 0; r < 8; ++r) Fproj[(size_t)(row0 + r) * JHD + j] = acc[r];
    }
}

// ---- Init: zero sync via WRITE-THROUGH agent stores (no dirty L2 zero-lines);
// labels=-1; out_lens passthrough ----
__global__ void init_kernel(const int* __restrict__ lens, float* ws,
                            float* __restrict__ out_lens_out,
                            float* __restrict__ labels_out) {
    int tid = threadIdx.x;
    int* sync = (int*)(ws + OFF_SYNC);
    for (int i = tid; i < 2048; i += 1024)
        __hip_atomic_store(sync + i, 0, __ATOMIC_RELAXED, __HIP_MEMORY_SCOPE_AGENT);
    for (int i = tid; i < BB * LBUF; i += 1024) labels_out[i] = -1.0f;
    if (tid < BB) out_lens_out[tid] = (float)lens[tid];
}

// ---- 8 per-XCD groups x 20 roles; 256 launched (32/XCD -> pure);
// L2 flushed at formation so sc0 tag/data lines are monotone-safe. ----
__global__ __launch_bounds__(1024) void decode_persistent(
    const int* __restrict__ lens,
    const float* __restrict__ Fproj,
    const float* __restrict__ W0,    // Whh0 [1280][320]
    const float* __restrict__ W1a,   // Wih1 [1280][320]
    const float* __restrict__ W1b,   // Whh1 [1280][320]
    const float* __restrict__ WjhR,  // [512][320]
    const float* __restrict__ Wj2T,  // [29][512]
    const float* __restrict__ EP, const float* __restrict__ b1,
    const float* __restrict__ bj2,
    float* MA, float* MB, float* JH, int* syncw,
    float* __restrict__ labels_out, float* __restrict__ counts_out) {

    const int tid = threadIdx.x;
    int* cntw  = syncw;           // [8], stride 16 ints
    int* arrw  = syncw + 128;
    int* tagsF = syncw + 256;     // fast: [8][3][32]
    int* tagsS = syncw + 1024;    // slow: [8][3][32]

    // ---------- formation: ticket local XCD, flush L2, rendezvous(256) ----------
    __shared__ int sGrp, sRole, sPure;
    if (tid == 0) {
        unsigned xr;
        asm volatile("s_getreg_b32 %0, hwreg(HW_REG_XCC_ID)" : "=s"(xr));
        int xcc = (int)(xr & 7u);
        int tkt = atomicAdd(cntw + xcc * 16, 1);
        // Flush this XCD's L2: write back + invalidate all stale dirty lines
        // (init's zeros, prior replays' mailboxes) BEFORE anyone produces epochs.
        asm volatile("buffer_wbl2 sc1" ::: "memory");
        asm volatile("s_waitcnt vmcnt(0)" ::: "memory");
        asm volatile("buffer_inv sc0 sc1" ::: "memory");
        asm volatile("s_waitcnt vmcnt(0)" ::: "memory");
        atomicAdd(arrw, 1);
        while (__hip_atomic_load(arrw, __ATOMIC_RELAXED, __HIP_MEMORY_SCOPE_AGENT) < NLAUNCH) { }
        int c[8];
        #pragma unroll
        for (int h = 0; h < 8; ++h)
            c[h] = __hip_atomic_load(cntw + h * 16, __ATOMIC_RELAXED,
                                     __HIP_MEMORY_SCOPE_AGENT);
        int grp = -1, role = 0;
        if (tkt < RPG) { grp = xcc; role = tkt; }
        else {
            int ov = tkt - RPG;
            for (int h = 0; h < xcc; ++h) ov += max(0, c[h] - RPG);
            int acc = 0;
            for (int g2 = 0; g2 < 8; ++g2) {
                int granted = min(c[g2], RPG);
                int d = RPG - granted;
                if (grp < 0 && ov < acc + d) { grp = g2; role = granted + (ov - acc); }
                acc += d;
            }
        }
        sGrp = grp; sRole = role;
        sPure = (grp >= 0 && c[grp] >= RPG) ? 1 : 0;
    }
    __syncthreads();
    const int grp = sGrp, role = sRole, pure = sPure;
    if (grp < 0) return;   // surplus block

    float* MAg = MA + grp * 640;
    float* MBg = MB + grp * 640;
    float* JHg = JH + grp * 1024;
    int* fA = tagsF + grp * 96;   int* sA = tagsS + grp * 96;
    int* fB = fA + 32;            int* sB = sA + 32;
    int* fC = fA + 64;            int* sC = sA + 64;

    extern __shared__ float dyn[];
    float* h0c = dyn;            // [2][320]
    float* h1c = dyn + 640;
    float* h0p = dyn + 1280;
    float* h1p = dyn + 1920;
    float* jhl = dyn + 2560;     // [2][512]

    __shared__ float gA[128], gB[128], lgL[64];
    __shared__ int lastL[2], cntL[2], contL[2], lenL[2], emitL[2];

    for (int i = tid; i < 640; i += 1024) { h0c[i] = 0.f; h1c[i] = 0.f; }
    if (tid < 2) {
        lastL[tid] = BLANKV; cntL[tid] = 0; contL[tid] = 0;
        lenL[tid] = lens[2 * grp + tid];
    }
    __syncthreads();
    const int maxL = max(lenL[0], lenL[1]);

    // matvec lanes: item(b0) | ks(b1-3) | r(b4-9)
    const int item = tid & 1;
    const int ks   = (tid >> 1) & 7;
    const int r    = tid >> 4;            // 0..63 local gate row
    const int gg   = r >> 4, rl = r & 15;
    const int hrow = role * HR + rl;      // 0..319
    const int kf   = ks * 40;
    const size_t wrow = (size_t)(gg * HH + hrow) * HH + kf;

    float c0cur = 0.f, c1cur = 0.f, c0p = 0.f, c1p = 0.f;

    for (int slot = 0; slot < 3 * maxL; ++slot) {
        const int t = slot / 3;
        const int s = slot - t * 3;
        const int e = slot + 1;

        // ===== Phase A: gates0 = Whh0@h0c (+EP); gB = Whh1@h1c partial =====
        {
            float a0 = 0.f, ab = 0.f;
            const f32x4* h0 = (const f32x4*)(h0c + item * HH + kf);
            const f32x4* h1 = (const f32x4*)(h1c + item * HH + kf);
            #pragma unroll
            for (int u = 0; u < 10; ++u) {
                f32x4 w  = *(const f32x4*)(W0 + wrow + u * 4);
                f32x4 h  = h0[u];
                a0 += w[0]*h[0] + w[1]*h[1] + w[2]*h[2] + w[3]*h[3];
                f32x4 w2 = *(const f32x4*)(W1b + wrow + u * 4);
                f32x4 h2 = h1[u];
                ab += w2[0]*h2[0] + w2[1]*h2[1] + w2[2]*h2[2] + w2[3]*h2[3];
            }
            a0 += __shfl_xor(a0, 2); a0 += __shfl_xor(a0, 4); a0 += __shfl_xor(a0, 8);
            ab += __shfl_xor(ab, 2); ab += __shfl_xor(ab, 4); ab += __shfl_xor(ab, 8);
            if (ks == 0) {
                gA[item * 64 + r] = a0 + EP[(size_t)lastL[item] * G4 + gg * HH + hrow];
                gB[item * 64 + r] = ab;
            }
        }
        __syncthreads();
        if (tid < 32) {
            int it = tid & 1, hr = tid >> 1;
            float xi = gA[it * 64 + hr];
            float xf = gA[it * 64 + 16 + hr];
            float xg = gA[it * 64 + 32 + hr];
            float xo = gA[it * 64 + 48 + hr];
            c0p = sigmoidf_(xf) * c0cur + sigmoidf_(xi) * tanhf(xg);
            st_data_f(MAg + it * HH + role * HR + hr, sigmoidf_(xo) * tanhf(c0p), pure);
        }
        asm volatile("s_waitcnt vmcnt(0)" ::: "memory");
        __syncthreads();
        if (tid == 0) { st_sc0_i(fA + role, e); st_tag(sA + role, e); }

        // ===== poll A + stage MA -> h0p =====
        if (tid < 64) poll_tags(fA, sA, RPG, e);
        __syncthreads();
        if (tid < 160) {
            f32x4 v = ld4_data(MAg + tid * 4, pure);
            int it = tid / 80, k = tid * 4 - it * 320;
            *(f32x4*)(h0p + it * HH + k) = v;
        }
        __syncthreads();

        // ===== Phase B: gates1 = Wih1@h0p + gB + b1 =====
        {
            float a1 = 0.f;
            const f32x4* hv = (const f32x4*)(h0p + item * HH + kf);
            #pragma unroll
            for (int u = 0; u < 10; ++u) {
                f32x4 w = *(const f32x4*)(W1a + wrow + u * 4);
                f32x4 h = hv[u];
                a1 += w[0]*h[0] + w[1]*h[1] + w[2]*h[2] + w[3]*h[3];
            }
            a1 += __shfl_xor(a1, 2); a1 += __shfl_xor(a1, 4); a1 += __shfl_xor(a1, 8);
            if (ks == 0)
                gA[item * 64 + r] = a1 + gB[item * 64 + r] + b1[gg * HH + hrow];
        }
        __syncthreads();
        if (tid < 32) {
            int it = tid & 1, hr = tid >> 1;
            float xi = gA[it * 64 + hr];
            float xf = gA[it * 64 + 16 + hr];
            float xg = gA[it * 64 + 32 + hr];
            float xo = gA[it * 64 + 48 + hr];
            c1p = sigmoidf_(xf) * c1cur + sigmoidf_(xi) * tanhf(xg);
            st_data_f(MBg + it * HH + role * HR + hr, sigmoidf_(xo) * tanhf(c1p), pure);
        }
        asm volatile("s_waitcnt vmcnt(0)" ::: "memory");
        __syncthreads();
        if (tid == 0) { st_sc0_i(fB + role, e); st_tag(sB + role, e); }

        // ===== poll B + stage MB -> h1p =====
        if (tid < 64) poll_tags(fB, sB, RPG, e);
        __syncthreads();
        if (tid < 160) {
            f32x4 v = ld4_data(MBg + tid * 4, pure);
            int it = tid / 80, k = tid * 4 - it * 320;
            *(f32x4*)(h1p + it * HH + k) = v;
        }
        __syncthreads();

        // ===== Phase C (roles 0..15): jh = relu(Fproj + Wjh@h1p) =====
        if (role < CROLES && tid < 512) {
            int jl = tid >> 4;                   // 0..31
            int jg2 = role * JR + jl;            // 0..511
            float a = 0.f;
            const f32x4* hv = (const f32x4*)(h1p + item * HH + kf);
            const float* wc = WjhR + (size_t)jg2 * HH + kf;
            #pragma unroll
            for (int u = 0; u < 10; ++u) {
                f32x4 w = *(const f32x4*)(wc + u * 4);
                f32x4 h = hv[u];
                a += w[0]*h[0] + w[1]*h[1] + w[2]*h[2] + w[3]*h[3];
            }
            a += __shfl_xor(a, 2); a += __shfl_xor(a, 4); a += __shfl_xor(a, 8);
            if (ks == 0) {
                float fp = Fproj[((size_t)(2 * grp + item) * TT + t) * JHD + jg2];
                st_data_f(JHg + item * JHD + jg2, fmaxf(a + fp, 0.f), pure);
            }
        }
        asm volatile("s_waitcnt vmcnt(0)" ::: "memory");
        __syncthreads();
        if (role < CROLES && tid == 0) { st_sc0_i(fC + role, e); st_tag(sC + role, e); }

        // ===== poll C + stage JH -> jhl =====
        if (tid < 64) poll_tags(fC, sC, CROLES, e);
        __syncthreads();
        if (tid < 256) {
            f32x4 v = ld4_data(JHg + tid * 4, pure);
            int it = tid / 128, k = tid * 4 - it * 512;
            *(f32x4*)(jhl + it * JHD + k) = v;
        }
        __syncthreads();

        // ===== Phase D (replicated): logits + argmax + commit =====
        if (tid < 928) {
            int k4 = tid & 15, it2 = (tid >> 4) & 1, v = tid >> 5;  // v 0..28
            const float* wv = Wj2T + (size_t)v * JHD + k4 * 32;
            const f32x4* hj = (const f32x4*)(jhl + it2 * JHD + k4 * 32);
            float a = 0.f;
            #pragma unroll
            for (int u2 = 0; u2 < 8; ++u2) {
                f32x4 w = *(const f32x4*)(wv + u2 * 4);
                f32x4 h = hj[u2];
                a += w[0]*h[0] + w[1]*h[1] + w[2]*h[2] + w[3]*h[3];
            }
            a += __shfl_xor(a, 1); a += __shfl_xor(a, 2);
            a += __shfl_xor(a, 4); a += __shfl_xor(a, 8);
            if (k4 == 0) lgL[it2 * 32 + v] = a + bj2[v];
        }
        __syncthreads();
        if (tid < 2) {
            float best = lgL[tid * 32];
            int k = 0;
            #pragma unroll
            for (int v = 1; v < VV; ++v) {
                float x = lgL[tid * 32 + v];
                if (x > best) { best = x; k = v; }
            }
            bool active = (t < lenL[tid]) && (s == 0 || contL[tid]);
            bool emit = active && (k != BLANKV);
            emitL[tid] = emit ? 1 : 0;
            if (emit) {
                if (role == 0)
                    labels_out[(size_t)(2 * grp + tid) * LBUF + cntL[tid]] = (float)k;
                cntL[tid]++; lastL[tid] = k; contL[tid] = 1;
            } else {
                contL[tid] = 0;
            }
        }
        __syncthreads();
        // commit: LDS copy of pending state; private c registers
        if (tid < 640) {
            int it = tid / 320, k = tid - it * 320;
            if (emitL[it]) {
                h0c[it * HH + k] = h0p[it * HH + k];
                h1c[it * HH + k] = h1p[it * HH + k];
            }
        }
        if (tid < 32 && emitL[tid & 1]) { c0cur = c0p; c1cur = c1p; }
        __syncthreads();
    }

    if (role == 0 && tid < 2) counts_out[2 * grp + tid] = (float)cntL[tid];
}

extern "C" void kernel_launch(void* const* d_in, const int* in_sizes, int n_in,
                              void* d_out, int out_size, void* d_ws, size_t ws_size,
                              hipStream_t stream) {
    const float* x      = (const float*)d_in[0];
    const int*   lens   = (const int*)d_in[1];
    const float* Wenc   = (const float*)d_in[2];
    const float* benc   = (const float*)d_in[3];
    const float* embed  = (const float*)d_in[4];
    const float* Wih0   = (const float*)d_in[5];
    const float* Whh0   = (const float*)d_in[6];
    const float* bih0   = (const float*)d_in[7];
    const float* bhh0   = (const float*)d_in[8];
    const float* Wih1   = (const float*)d_in[9];
    const float* Whh1   = (const float*)d_in[10];
    const float* bih1   = (const float*)d_in[11];
    const float* bhh1   = (const float*)d_in[12];
    const float* Wj1    = (const float*)d_in[13];
    const float* bj1    = (const float*)d_in[14];
    const float* Wj2    = (const float*)d_in[15];
    const float* bj2    = (const float*)d_in[16];

    float* out = (float*)d_out;
    float* logits_out   = out;
    float* out_lens_out = out + (size_t)BB * TT * E_DIM;
    float* labels_out   = out_lens_out + BB;
    float* counts_out   = labels_out + (size_t)BB * LBUF;

    float* ws    = (float*)d_ws;
    float* Fproj = ws + OFF_FPROJ;
    float* WjhR  = ws + OFF_WJHR;
    float* EP    = ws + OFF_EP;
    float* b1    = ws + OFF_B1;
    float* Wj2T  = ws + OFF_WJ2T;
    float* MA    = ws + OFF_MA;
    float* MB    = ws + OFF_MB;
    float* JH    = ws + OFF_JH;
    int*   syncw = (int*)(ws + OFF_SYNC);

    // Force 1 block/CU -> exactly 32 blocks/XCD -> every group pure
    const int dynBytes = 84 * 1024;
    hipFuncSetAttribute((const void*)decode_persistent,
                        hipFuncAttributeMaxDynamicSharedMemorySize, dynBytes);

    {
        int total = 163840 + G4 + VV * JHD;
        prep_t_kernel<<<(total + 255) / 256, 256, 0, stream>>>(
            Wj1, bih1, bhh1, Wj2, WjhR, b1, Wj2T);
    }
    ep_kernel<<<VV, 256, 0, stream>>>(embed, Wih0, bih0, bhh0, EP);
    enc_fproj_kernel<<<(BB * TT) / 8, 512, 0, stream>>>(x, Wenc, benc, Wj1, bj1,
                                                        logits_out, Fproj);
    init_kernel<<<1, 1024, 0, stream>>>(lens, ws, out_lens_out, labels_out);
    decode_persistent<<<NLAUNCH, 1024, dynBytes, stream>>>(
        lens, Fproj, Whh0, Wih1, Whh1, WjhR, Wj2T, EP, b1, bj2,
        MA, MB, JH, syncw, labels_out, counts_out);
}

// Round 13
// 8309.587 us; speedup vs baseline: 4.9796x; 2.2131x over previous
//
#include <hip/hip_runtime.h>
#include <math.h>

// Problem constants
#define BB 16
#define TT 128
#define F_IN 240
#define E_DIM 1024
#define HH 320
#define G4 1280
#define JHD 512
#define VV 29
#define BLANKV 28
#define MAXSYM 3
#define LBUF (TT*MAXSYM)

#define GROUPS 8
#define RPG 32            // roles per group = all CUs of the XCD
#define NLAUNCH 256       // launched blocks (1/CU)
#define HRR 10            // h-rows per role (320/32)
#define JRR 16            // joint rows per role (512/32)
#define WP 324            // padded LDS pitch for weight rows (floats)

// Workspace layout (float offsets)
#define OFF_FPROJ 0ul                        // 2048*512
#define OFF_WJHR  1048576ul                  // 512*320
#define OFF_EP    (OFF_WJHR + 163840ul)      // 29*1280
#define OFF_B1    (OFF_EP + 37120ul)         // 1280
#define OFF_WJ2T  (OFF_B1 + 1280ul)          // 29*512 = 14848
#define OFF_MA    (OFF_WJ2T + 14848ul)       // [8][2][320] = 5120
#define OFF_MB    (OFF_MA + 5120ul)          // 5120
#define OFF_JH    (OFF_MB + 5120ul)          // [8][2][512] = 8192
#define OFF_SYNC  (OFF_JH + 8192ul)          // 2048 ints

typedef float f32x4 __attribute__((ext_vector_type(4)));

__device__ __forceinline__ float sigmoidf_(float x) {
    return 1.0f / (1.0f + expf(-x));
}
// LLC-scope (agent) tag ops — round-10 proven semantics
__device__ __forceinline__ int ld_tag(const int* p) {
    return __hip_atomic_load(p, __ATOMIC_RELAXED, __HIP_MEMORY_SCOPE_AGENT);
}
__device__ __forceinline__ void st_tag(int* p, int v) {
    __hip_atomic_store(p, v, __ATOMIC_RELAXED, __HIP_MEMORY_SCOPE_AGENT);
}
// data ops: pure group -> sc0 (XCD-local L2); impure -> sc0 sc1 (LLC)
__device__ __forceinline__ void st_data_f(float* p, float v, int pure) {
    if (pure) asm volatile("global_store_dword %0, %1, off sc0" :: "v"(p), "v"(v) : "memory");
    else      asm volatile("global_store_dword %0, %1, off sc0 sc1" :: "v"(p), "v"(v) : "memory");
}
__device__ __forceinline__ f32x4 ld4_data(const float* p, int pure) {
    f32x4 v;
    if (pure) asm volatile("global_load_dwordx4 %0, %1, off sc0\n\ts_waitcnt vmcnt(0)"
                           : "=&v"(v) : "v"(p) : "memory");
    else      asm volatile("global_load_dwordx4 %0, %1, off sc0 sc1\n\ts_waitcnt vmcnt(0)"
                           : "=&v"(v) : "v"(p) : "memory");
    return v;
}
// wave-0 poll: LLC tags, no sleep (round-10 form)
__device__ __forceinline__ void poll_tags(const int* tagp, int n, int e) {
    int lane = threadIdx.x;   // caller guarantees tid < 64
    while (__ballot((lane < n) && (ld_tag(tagp + lane) < e)) != 0ull) { }
}

// ---- Prep: WjhR[j][k]=Wj1[1024+k][j]; b1=bih1+bhh1; Wj2T[v][k]=Wj2[k][v] ----
__global__ void prep_t_kernel(const float* __restrict__ Wj1,
                              const float* __restrict__ bih1,
                              const float* __restrict__ bhh1,
                              const float* __restrict__ Wj2,
                              float* __restrict__ WjhR, float* __restrict__ b1,
                              float* __restrict__ Wj2T) {
    int idx = blockIdx.x * 256 + threadIdx.x;
    if (idx < 163840) {
        int j = idx / 320, k = idx - j * 320;
        WjhR[idx] = Wj1[(size_t)(1024 + k) * JHD + j];
        return;
    }
    int i2 = idx - 163840;
    if (i2 < G4) { b1[i2] = bih1[i2] + bhh1[i2]; return; }
    int e = i2 - G4;
    if (e < VV * JHD) {
        int v = e >> 9, k = e & 511;
        Wj2T[e] = Wj2[(size_t)k * VV + v];
    }
}

// ---- Prep: EP[v][j] = embed[v]@Wih0[j,:] + bih0[j]+bhh0[j]; row 28 = bias only
__global__ void ep_kernel(const float* __restrict__ embed,
                          const float* __restrict__ Wih0,
                          const float* __restrict__ bih0,
                          const float* __restrict__ bhh0,
                          float* __restrict__ EP) {
    __shared__ __align__(16) float es[HH];
    int v = blockIdx.x;
    for (int k = threadIdx.x; k < HH; k += 256)
        es[k] = (v < VV - 1) ? embed[v * HH + k] : 0.0f;
    __syncthreads();
    for (int j = threadIdx.x; j < G4; j += 256) {
        float acc = bih0[j] + bhh0[j];
        if (v < VV - 1) {
            const float4* wr = (const float4*)(Wih0 + (size_t)j * HH);
            const float4* ev = (const float4*)es;
            #pragma unroll 4
            for (int k4 = 0; k4 < HH / 4; ++k4) {
                float4 w = wr[k4], e = ev[k4];
                acc += w.x * e.x + w.y * e.y + w.z * e.z + w.w * e.w;
            }
        }
        EP[v * G4 + j] = acc;
    }
}

// ---- Encoder + F_proj fused ----
__global__ __launch_bounds__(512) void enc_fproj_kernel(
    const float* __restrict__ x, const float* __restrict__ Wenc,
    const float* __restrict__ benc, const float* __restrict__ Wj1,
    const float* __restrict__ bj1,
    float* __restrict__ logits_out, float* __restrict__ Fproj) {
    __shared__ float xs[8][F_IN];
    __shared__ float ls[8][E_DIM];
    int row0 = blockIdx.x * 8;
    int tid = threadIdx.x;
    for (int i = tid; i < 8 * F_IN; i += 512)
        xs[i / F_IN][i % F_IN] = x[(size_t)row0 * F_IN + i];
    __syncthreads();
    for (int j = tid; j < E_DIM; j += 512) {
        float acc[8];
        float bv = benc[j];
        #pragma unroll
        for (int r = 0; r < 8; ++r) acc[r] = bv;
        for (int k = 0; k < F_IN; ++k) {
            float w = Wenc[(size_t)k * E_DIM + j];
            #pragma unroll
            for (int r = 0; r < 8; ++r) acc[r] += xs[r][k] * w;
        }
        #pragma unroll
        for (int r = 0; r < 8; ++r) {
            ls[r][j] = acc[r];
            logits_out[(size_t)(row0 + r) * E_DIM + j] = acc[r];
        }
    }
    __syncthreads();
    {
        int j = tid;
        float acc[8];
        float bv = bj1[j];
        #pragma unroll
        for (int r = 0; r < 8; ++r) acc[r] = bv;
        for (int k = 0; k < E_DIM; ++k) {
            float w = Wj1[(size_t)k * JHD + j];
            #pragma unroll
            for (int r = 0; r < 8; ++r) acc[r] += ls[r][k] * w;
        }
        #pragma unroll
        for (int r = 0; r < 8; ++r) Fproj[(size_t)(row0 + r) * JHD + j] = acc[r];
    }
}

// ---- Init: zero sync via write-through agent stores; labels=-1 ----
__global__ void init_kernel(const int* __restrict__ lens, float* ws,
                            float* __restrict__ out_lens_out,
                            float* __restrict__ labels_out) {
    int tid = threadIdx.x;
    int* sync = (int*)(ws + OFF_SYNC);
    for (int i = tid; i < 2048; i += 1024)
        __hip_atomic_store(sync + i, 0, __ATOMIC_RELAXED, __HIP_MEMORY_SCOPE_AGENT);
    for (int i = tid; i < BB * LBUF; i += 1024) labels_out[i] = -1.0f;
    if (tid < BB) out_lens_out[tid] = (float)lens[tid];
}

// ---- 8 per-XCD groups x 32 roles (all CUs); W0/W1a slices in LDS;
// W1b/Wjh stream L2-resident; LLC tags (round-10); sc0 data. ----
__global__ __launch_bounds__(1024) void decode_persistent(
    const int* __restrict__ lens,
    const float* __restrict__ Fproj,
    const float* __restrict__ W0,    // Whh0 [1280][320]
    const float* __restrict__ W1a,   // Wih1 [1280][320]
    const float* __restrict__ W1b,   // Whh1 [1280][320]
    const float* __restrict__ WjhR,  // [512][320]
    const float* __restrict__ Wj2T,  // [29][512]
    const float* __restrict__ EP, const float* __restrict__ b1,
    const float* __restrict__ bj2,
    float* MA, float* MB, float* JH, int* syncw,
    float* __restrict__ labels_out, float* __restrict__ counts_out) {

    const int tid = threadIdx.x;
    int* cntw  = syncw;           // [8], stride 16 ints
    int* arrw  = syncw + 128;
    int* tags  = syncw + 256;     // [8][3][32]

    // ---------- formation: ticket local XCD, flush L2, rendezvous(256) ----------
    __shared__ int sGrp, sRole, sPure;
    if (tid == 0) {
        unsigned xr;
        asm volatile("s_getreg_b32 %0, hwreg(HW_REG_XCC_ID)" : "=s"(xr));
        int xcc = (int)(xr & 7u);
        int tkt = atomicAdd(cntw + xcc * 16, 1);
        // one-time L2 writeback+invalidate: kill stale mailbox lines from
        // prior replays before any epoch of this replay is produced
        asm volatile("buffer_wbl2 sc1" ::: "memory");
        asm volatile("s_waitcnt vmcnt(0)" ::: "memory");
        asm volatile("buffer_inv sc0 sc1" ::: "memory");
        asm volatile("s_waitcnt vmcnt(0)" ::: "memory");
        atomicAdd(arrw, 1);
        while (__hip_atomic_load(arrw, __ATOMIC_RELAXED, __HIP_MEMORY_SCOPE_AGENT) < NLAUNCH) { }
        int c[8];
        #pragma unroll
        for (int h = 0; h < 8; ++h)
            c[h] = __hip_atomic_load(cntw + h * 16, __ATOMIC_RELAXED,
                                     __HIP_MEMORY_SCOPE_AGENT);
        int grp = -1, role = 0;
        if (tkt < RPG) { grp = xcc; role = tkt; }
        else {
            int ov = tkt - RPG;
            for (int h = 0; h < xcc; ++h) ov += max(0, c[h] - RPG);
            int acc = 0;
            for (int g2 = 0; g2 < 8; ++g2) {
                int granted = min(c[g2], RPG);
                int d = RPG - granted;
                if (grp < 0 && ov < acc + d) { grp = g2; role = granted + (ov - acc); }
                acc += d;
            }
        }
        sGrp = grp; sRole = role;
        sPure = (grp >= 0 && c[grp] >= RPG) ? 1 : 0;
    }
    __syncthreads();
    const int grp = sGrp, role = sRole, pure = sPure;
    if (grp < 0) return;   // surplus block

    float* MAg = MA + grp * 640;
    float* MBg = MB + grp * 640;
    float* JHg = JH + grp * 1024;
    int* tagA = tags + grp * 96;
    int* tagB = tagA + 32;
    int* tagC = tagA + 64;

    extern __shared__ float dyn[];
    float* W0L  = dyn;                 // [40][WP] this role's Whh0 slice
    float* W1aL = dyn + 40 * WP;       // [40][WP] this role's Wih1 slice
    float* h0c  = dyn + 80 * WP;       // [2][320]
    float* h1c  = h0c + 640;
    float* h0p  = h1c + 640;
    float* h1p  = h0p + 640;
    float* jhl  = h1p + 640;           // [2][512]

    __shared__ float gA[80], gB[80], lgL[64];
    __shared__ int lastL[2], cntL[2], contL[2], lenL[2], emitL[2];

    // preload W0/W1a slices (40 gate rows each) into LDS
    for (int idx = tid; idx < 40 * 320; idx += 1024) {
        int rr = idx / 320, k = idx - rr * 320;
        int ggp = rr / HRR, rlp = rr - ggp * HRR;
        size_t grow = (size_t)(ggp * HH + role * HRR + rlp) * HH + k;
        W0L[rr * WP + k]  = W0[grow];
        W1aL[rr * WP + k] = W1a[grow];
    }
    for (int i = tid; i < 640; i += 1024) { h0c[i] = 0.f; h1c[i] = 0.f; }
    if (tid < 2) {
        lastL[tid] = BLANKV; cntL[tid] = 0; contL[tid] = 0;
        lenL[tid] = lens[2 * grp + tid];
    }
    __syncthreads();
    const int maxL = max(lenL[0], lenL[1]);

    // matvec lanes: item(b0) | ks(b1-3) | r(b4..): r<40 active
    const int item = tid & 1;
    const int ks   = (tid >> 1) & 7;
    const int r    = tid >> 4;            // 0..63; active r<40
    const bool mv  = (r < 40);
    const int gg   = r / HRR, rl = r - gg * HRR;
    const int hrow = role * HRR + rl;     // 0..319
    const int kf   = ks * 40;
    const size_t wrow = (size_t)(gg * HH + hrow) * HH + kf;   // streamed weights
    const int lrow = r * WP + kf;                             // LDS weights

    // phase-C lanes (tid<256): item | ks | jl(0..15)
    const int jlC = tid >> 4;             // 0..15 when tid<256

    float c0cur = 0.f, c1cur = 0.f, c0p = 0.f, c1p = 0.f;

    for (int slot = 0; slot < 3 * maxL; ++slot) {
        const int t = slot / 3;
        const int s = slot - t * 3;
        const int e = slot + 1;

        // ===== Phase A: gates0 = W0L@h0c (+EP); gB = W1b@h1c (streamed) =====
        if (mv) {
            float a0 = 0.f, ab = 0.f;
            const f32x4* h0 = (const f32x4*)(h0c + item * HH + kf);
            const f32x4* h1 = (const f32x4*)(h1c + item * HH + kf);
            const f32x4* w0l = (const f32x4*)(W0L + lrow);
            #pragma unroll
            for (int u = 0; u < 10; ++u) {
                f32x4 w = w0l[u];
                f32x4 h = h0[u];
                a0 += w[0]*h[0] + w[1]*h[1] + w[2]*h[2] + w[3]*h[3];
                f32x4 w2 = *(const f32x4*)(W1b + wrow + u * 4);
                f32x4 h2 = h1[u];
                ab += w2[0]*h2[0] + w2[1]*h2[1] + w2[2]*h2[2] + w2[3]*h2[3];
            }
            a0 += __shfl_xor(a0, 2); a0 += __shfl_xor(a0, 4); a0 += __shfl_xor(a0, 8);
            ab += __shfl_xor(ab, 2); ab += __shfl_xor(ab, 4); ab += __shfl_xor(ab, 8);
            if (ks == 0) {
                gA[item * 40 + r] = a0 + EP[(size_t)lastL[item] * G4 + gg * HH + hrow];
                gB[item * 40 + r] = ab;
            }
        }
        __syncthreads();
        if (tid < 20) {
            int it = tid & 1, hr = tid >> 1;   // hr 0..9
            float xi = gA[it * 40 + hr];
            float xf = gA[it * 40 + 10 + hr];
            float xg = gA[it * 40 + 20 + hr];
            float xo = gA[it * 40 + 30 + hr];
            c0p = sigmoidf_(xf) * c0cur + sigmoidf_(xi) * tanhf(xg);
            st_data_f(MAg + it * HH + role * HRR + hr, sigmoidf_(xo) * tanhf(c0p), pure);
        }
        asm volatile("s_waitcnt vmcnt(0)" ::: "memory");
        __syncthreads();
        if (tid == 0) st_tag(tagA + role, e);

        // ===== poll A + stage MA -> h0p =====
        if (tid < 64) poll_tags(tagA, RPG, e);
        __syncthreads();
        if (tid < 160) {
            f32x4 v = ld4_data(MAg + tid * 4, pure);
            int it = tid / 80, k = tid * 4 - it * 320;
            *(f32x4*)(h0p + it * HH + k) = v;
        }
        __syncthreads();

        // ===== Phase B: gates1 = W1aL@h0p + gB + b1 =====
        if (mv) {
            float a1 = 0.f;
            const f32x4* hv = (const f32x4*)(h0p + item * HH + kf);
            const f32x4* w1l = (const f32x4*)(W1aL + lrow);
            #pragma unroll
            for (int u = 0; u < 10; ++u) {
                f32x4 w = w1l[u];
                f32x4 h = hv[u];
                a1 += w[0]*h[0] + w[1]*h[1] + w[2]*h[2] + w[3]*h[3];
            }
            a1 += __shfl_xor(a1, 2); a1 += __shfl_xor(a1, 4); a1 += __shfl_xor(a1, 8);
            if (ks == 0)
                gA[item * 40 + r] = a1 + gB[item * 40 + r] + b1[gg * HH + hrow];
        }
        __syncthreads();
        if (tid < 20) {
            int it = tid & 1, hr = tid >> 1;
            float xi = gA[it * 40 + hr];
            float xf = gA[it * 40 + 10 + hr];
            float xg = gA[it * 40 + 20 + hr];
            float xo = gA[it * 40 + 30 + hr];
            c1p = sigmoidf_(xf) * c1cur + sigmoidf_(xi) * tanhf(xg);
            st_data_f(MBg + it * HH + role * HRR + hr, sigmoidf_(xo) * tanhf(c1p), pure);
        }
        asm volatile("s_waitcnt vmcnt(0)" ::: "memory");
        __syncthreads();
        if (tid == 0) st_tag(tagB + role, e);

        // ===== poll B + stage MB -> h1p =====
        if (tid < 64) poll_tags(tagB, RPG, e);
        __syncthreads();
        if (tid < 160) {
            f32x4 v = ld4_data(MBg + tid * 4, pure);
            int it = tid / 80, k = tid * 4 - it * 320;
            *(f32x4*)(h1p + it * HH + k) = v;
        }
        __syncthreads();

        // ===== Phase C (all roles): jh slice (16 j) = relu(Fproj + Wjh@h1p) =====
        if (tid < 256) {
            int jg2 = role * JRR + jlC;          // 0..511
            float a = 0.f;
            const f32x4* hv = (const f32x4*)(h1p + item * HH + kf);
            const float* wc = WjhR + (size_t)jg2 * HH + kf;
            #pragma unroll
            for (int u = 0; u < 10; ++u) {
                f32x4 w = *(const f32x4*)(wc + u * 4);
                f32x4 h = hv[u];
                a += w[0]*h[0] + w[1]*h[1] + w[2]*h[2] + w[3]*h[3];
            }
            a += __shfl_xor(a, 2); a += __shfl_xor(a, 4); a += __shfl_xor(a, 8);
            if (ks == 0) {
                float fp = Fproj[((size_t)(2 * grp + item) * TT + t) * JHD + jg2];
                st_data_f(JHg + item * JHD + jg2, fmaxf(a + fp, 0.f), pure);
            }
        }
        asm volatile("s_waitcnt vmcnt(0)" ::: "memory");
        __syncthreads();
        if (tid == 0) st_tag(tagC + role, e);

        // ===== poll C + stage JH -> jhl =====
        if (tid < 64) poll_tags(tagC, RPG, e);
        __syncthreads();
        if (tid < 256) {
            f32x4 v = ld4_data(JHg + tid * 4, pure);
            int it = tid / 128, k = tid * 4 - it * 512;
            *(f32x4*)(jhl + it * JHD + k) = v;
        }
        __syncthreads();

        // ===== Phase D (replicated): logits + argmax + commit =====
        if (tid < 928) {
            int k4 = tid & 15, it2 = (tid >> 4) & 1, v = tid >> 5;  // v 0..28
            const float* wv = Wj2T + (size_t)v * JHD + k4 * 32;
            const f32x4* hj = (const f32x4*)(jhl + it2 * JHD + k4 * 32);
            float a = 0.f;
            #pragma unroll
            for (int u2 = 0; u2 < 8; ++u2) {
                f32x4 w = *(const f32x4*)(wv + u2 * 4);
                f32x4 h = hj[u2];
                a += w[0]*h[0] + w[1]*h[1] + w[2]*h[2] + w[3]*h[3];
            }
            a += __shfl_xor(a, 1); a += __shfl_xor(a, 2);
            a += __shfl_xor(a, 4); a += __shfl_xor(a, 8);
            if (k4 == 0) lgL[it2 * 32 + v] = a + bj2[v];
        }
        __syncthreads();
        if (tid < 2) {
            float best = lgL[tid * 32];
            int k = 0;
            #pragma unroll
            for (int v = 1; v < VV; ++v) {
                float x = lgL[tid * 32 + v];
                if (x > best) { best = x; k = v; }
            }
            bool active = (t < lenL[tid]) && (s == 0 || contL[tid]);
            bool emit = active && (k != BLANKV);
            emitL[tid] = emit ? 1 : 0;
            if (emit) {
                if (role == 0)
                    labels_out[(size_t)(2 * grp + tid) * LBUF + cntL[tid]] = (float)k;
                cntL[tid]++; lastL[tid] = k; contL[tid] = 1;
            } else {
                contL[tid] = 0;
            }
        }
        __syncthreads();
        // commit: LDS copy of pending state; private c registers
        if (tid < 640) {
            int it = tid / 320, k = tid - it * 320;
            if (emitL[it]) {
                h0c[it * HH + k] = h0p[it * HH + k];
                h1c[it * HH + k] = h1p[it * HH + k];
            }
        }
        if (tid < 20 && emitL[tid & 1]) { c0cur = c0p; c1cur = c1p; }
        __syncthreads();
    }

    if (role == 0 && tid < 2) counts_out[2 * grp + tid] = (float)cntL[tid];
}

extern "C" void kernel_launch(void* const* d_in, const int* in_sizes, int n_in,
                              void* d_out, int out_size, void* d_ws, size_t ws_size,
                              hipStream_t stream) {
    const float* x      = (const float*)d_in[0];
    const int*   lens   = (const int*)d_in[1];
    const float* Wenc   = (const float*)d_in[2];
    const float* benc   = (const float*)d_in[3];
    const float* embed  = (const float*)d_in[4];
    const float* Wih0   = (const float*)d_in[5];
    const float* Whh0   = (const float*)d_in[6];
    const float* bih0   = (const float*)d_in[7];
    const float* bhh0   = (const float*)d_in[8];
    const float* Wih1   = (const float*)d_in[9];
    const float* Whh1   = (const float*)d_in[10];
    const float* bih1   = (const float*)d_in[11];
    const float* bhh1   = (const float*)d_in[12];
    const float* Wj1    = (const float*)d_in[13];
    const float* bj1    = (const float*)d_in[14];
    const float* Wj2    = (const float*)d_in[15];
    const float* bj2    = (const float*)d_in[16];

    float* out = (float*)d_out;
    float* logits_out   = out;
    float* out_lens_out = out + (size_t)BB * TT * E_DIM;
    float* labels_out   = out_lens_out + BB;
    float* counts_out   = labels_out + (size_t)BB * LBUF;

    float* ws    = (float*)d_ws;
    float* Fproj = ws + OFF_FPROJ;
    float* WjhR  = ws + OFF_WJHR;
    float* EP    = ws + OFF_EP;
    float* b1    = ws + OFF_B1;
    float* Wj2T  = ws + OFF_WJ2T;
    float* MA    = ws + OFF_MA;
    float* MB    = ws + OFF_MB;
    float* JH    = ws + OFF_JH;
    int*   syncw = (int*)(ws + OFF_SYNC);

    // dyn LDS: 2 weight slices [40][WP] + h bufs + jhl -> 1 block/CU
    const int dynBytes = (80 * WP + 4 * 640 + 2 * JHD) * 4;   // 118,016 B
    hipFuncSetAttribute((const void*)decode_persistent,
                        hipFuncAttributeMaxDynamicSharedMemorySize, dynBytes);

    {
        int total = 163840 + G4 + VV * JHD;
        prep_t_kernel<<<(total + 255) / 256, 256, 0, stream>>>(
            Wj1, bih1, bhh1, Wj2, WjhR, b1, Wj2T);
    }
    ep_kernel<<<VV, 256, 0, stream>>>(embed, Wih0, bih0, bhh0, EP);
    enc_fproj_kernel<<<(BB * TT) / 8, 512, 0, stream>>>(x, Wenc, benc, Wj1, bj1,
                                                        logits_out, Fproj);
    init_kernel<<<1, 1024, 0, stream>>>(lens, ws, out_lens_out, labels_out);
    decode_persistent<<<NLAUNCH, 1024, dynBytes, stream>>>(
        lens, Fproj, Whh0, Wih1, Whh1, WjhR, Wj2T, EP, b1, bj2,
        MA, MB, JH, syncw, labels_out, counts_out);
}